// Round 12
// baseline (158.592 us; speedup 1.0000x reference)
//
#include <hip/hip_runtime.h>
#include <hip/hip_bf16.h>

typedef __attribute__((ext_vector_type(8))) short short8;
typedef __attribute__((ext_vector_type(4))) float f32x4;

#define BQ 8
#define SEQ 4096
#define CH 512
#define NHD 8
#define HD 64
#define K3C 1536
#define MTOK 32768
#define NSPL 8

__device__ __forceinline__ float bfu2f(unsigned int u) {
  u <<= 16;
  float f;
  __builtin_memcpy(&f, &u, 4);
  return f;
}
__device__ __forceinline__ unsigned short f2bfu(float x) {
  __hip_bfloat16 h = __float2bfloat16(x);
  unsigned short u;
  __builtin_memcpy(&u, &h, 2);
  return u;
}

__device__ __forceinline__ void gload_lds16(const void* g, void* l) {
  __builtin_amdgcn_global_load_lds(
      (const __attribute__((address_space(1))) unsigned int*)g,
      (__attribute__((address_space(3))) unsigned int*)l, 16, 0, 0);
}

// ---------------- cast kernels ----------------
__global__ __launch_bounds__(256) void cast_f32_bf16(const float* __restrict__ in,
                                                     unsigned short* __restrict__ out, int n4) {
  int stride = gridDim.x * blockDim.x;
  for (int i = blockIdx.x * blockDim.x + threadIdx.x; i < n4; i += stride) {
    float4 v = reinterpret_cast<const float4*>(in)[i];
    ushort4 o;
    o.x = f2bfu(v.x); o.y = f2bfu(v.y); o.z = f2bfu(v.z); o.w = f2bfu(v.w);
    reinterpret_cast<ushort4*>(out)[i] = o;
  }
}

// in: f32 [R][Cc] row-major -> out: bf16 [Cc][R]
__global__ __launch_bounds__(256) void transpose_cast(const float* __restrict__ in,
                                                      unsigned short* __restrict__ out,
                                                      int R, int Cc) {
  __shared__ float tile[32][33];
  const int tx = threadIdx.x, ty = threadIdx.y;  // 32 x 8
  const int c0 = blockIdx.x * 32, r0 = blockIdx.y * 32;
  #pragma unroll
  for (int dy = 0; dy < 32; dy += 8)
    tile[ty + dy][tx] = in[(size_t)(r0 + ty + dy) * Cc + (c0 + tx)];
  __syncthreads();
  #pragma unroll
  for (int dy = 0; dy < 32; dy += 8)
    out[(size_t)(c0 + ty + dy) * R + (r0 + tx)] = f2bfu(tile[tx][ty + dy]);
}

// --- 256x128 tile, 8 waves x (64x64), BK=32, 3-ring 72KB, stage-ahead depth 2 ---
// (round-11 verified schedule; see its hazard ledger.)
// MODE 0: QKV, A=xb [M][K] K-major.  Q/K blocks (n0<1024): LDS-transpose -> qkT;
//         V blocks: direct vb[bh][n][d] stores.
// MODE 2: final GEMM out = vbcat @ WmodT^T + bias.  A rows m=(b,n): element
//         (m, k=h*64+d) at vb[((b*8+h)*4096+n)*64+d]; per-tile h = kt>>6 is
//         uniform (kt%64 in {0,32}, intra-tile k-offset < 32).  Bt = WmodT + b*512*512.
template <int MODE>
__global__ __launch_bounds__(512, 4) void gemm256(const unsigned short* __restrict__ A,
                                                  const unsigned short* __restrict__ Bt,
                                                  void* __restrict__ out0,
                                                  void* __restrict__ out1,
                                                  const float* __restrict__ bias,
                                                  int M, int Nn, int Kk, int nbx) {
  __shared__ __align__(16) char lds[73728];
  const int nwg = gridDim.x;
  int wg = blockIdx.x;
  wg = (wg & 7) * (nwg >> 3) + (wg >> 3);  // XCD swizzle (nwg % 8 == 0)
  const int bx = wg % nbx, by = wg / nbx;
  const int m0 = by * 256, n0 = bx * 128;

  const int tid = threadIdx.x, wave = tid >> 6, lane = tid & 63;
  const int wr = wave >> 1, wc = wave & 1;
  const int l15 = lane & 15, lg = lane >> 4;
  const int T = Kk >> 5;

  f32x4 acc[4][4] = {};  // 64 regs: wave tile 64 tokens x 64 cols
  short8 af[4], bf[4];

  // staging thread->slot precompute (slot L = tid)
  const int prowA = tid >> 3, sA = tid & 7;
  const int slinA = sA ^ (prowA & 7);
  const int mA = ((slinA >> 2) << 7) + prowA, kA = (slinA & 3) << 3;
  const int prow2 = prowA + 64;                 // second A half: L2 = tid + 512
  const int slin2 = sA ^ (prow2 & 7);
  const int m2 = ((slin2 >> 2) << 7) + prow2, k2 = (slin2 & 3) << 3;
  const int prowB = tid >> 3, sB = tid & 7;
  const int slinB = sB ^ (prowB & 7);
  const int nB = ((slinB >> 2) << 6) + prowB, kB = (slinB & 3) << 3;
  const int woff = wave * 1024;                 // per-wave LDS dest offset

  // MODE 2 bases
  const int bidx = m0 >> 12;                    // batch index
  const unsigned short* Bt2 = Bt + (size_t)bidx * 262144;
  const int nrow1 = (m0 & 4095) + mA, nrow2 = (m0 & 4095) + m2;

  auto stageAB = [&](int kt, char* buf) {
    if (MODE == 2) {
      const unsigned short* Abase =
          A + (size_t)(bidx * 8 + (kt >> 6)) * 4096 * 64 + (kt & 32);
      gload_lds16(Abase + (size_t)nrow1 * 64 + kA, buf + woff);
      gload_lds16(Abase + (size_t)nrow2 * 64 + k2, buf + 8192 + woff);
      gload_lds16(Bt2 + (size_t)(n0 + nB) * Kk + kt + kB, buf + 16384 + woff);
    } else {
      gload_lds16(A + (size_t)(m0 + mA) * Kk + kt + kA, buf + woff);
      gload_lds16(A + (size_t)(m0 + m2) * Kk + kt + k2, buf + 8192 + woff);
      gload_lds16(Bt + (size_t)(n0 + nB) * Kk + kt + kB, buf + 16384 + woff);
    }
  };

  auto dsA = [&](const char* bufc) {
    #pragma unroll
    for (int fr = 0; fr < 4; ++fr) {
      const int m = wr * 64 + fr * 16 + l15;
      const int prow = m & 127;
      const int s = ((m >> 7) * 4 + lg) ^ (l15 & 7);
      af[fr] = *reinterpret_cast<const short8*>(bufc + prow * 128 + (s << 4));
    }
  };
  auto dsB = [&](const char* bufc) {
    #pragma unroll
    for (int fc = 0; fc < 4; ++fc) {
      const int prow = fc * 16 + l15;   // n&63
      const int s = (wc * 4 + lg) ^ (l15 & 7);
      bf[fc] = *reinterpret_cast<const short8*>(bufc + 16384 + prow * 128 + (s << 4));
    }
  };

  // prologue: stage tiles 0 and 1
  stageAB(0, lds);
  stageAB(32, lds + 24576);
  asm volatile("s_waitcnt vmcnt(3)" ::: "memory");  // tile 0 landed, tile 1 in flight
  __builtin_amdgcn_s_barrier();

  char* p0 = lds;
  char* p1 = lds + 24576;
  char* p2 = lds + 49152;

  for (int t = 0; t < T; ++t) {
    dsA(p0);
    dsB(p0);
    const bool st2 = (t + 2 < T);
    if (st2) stageAB((t + 2) << 5, p2);
    __builtin_amdgcn_s_setprio(1);
    #pragma unroll
    for (int fr = 0; fr < 4; ++fr)
      #pragma unroll
      for (int fc = 0; fc < 4; ++fc)
        acc[fr][fc] = __builtin_amdgcn_mfma_f32_16x16x32_bf16(
            af[fr], bf[fc], acc[fr][fc], 0, 0, 0);
    __builtin_amdgcn_s_setprio(0);
    if (t + 1 < T) {
      if (st2) asm volatile("s_waitcnt vmcnt(3)" ::: "memory");
      else     asm volatile("s_waitcnt vmcnt(0)" ::: "memory");
      __builtin_amdgcn_s_barrier();
    }
    char* tmp = p0; p0 = p1; p1 = p2; p2 = tmp;
  }

  // ---------------- epilogue ----------------
  if (MODE == 2) {
    #pragma unroll
    for (int fr = 0; fr < 4; ++fr)
      #pragma unroll
      for (int fc = 0; fc < 4; ++fc) {
        const int row0 = m0 + wr * 64 + fr * 16 + lg * 4;
        const int col = n0 + wc * 64 + fc * 16 + l15;
        #pragma unroll
        for (int v = 0; v < 4; ++v)
          reinterpret_cast<float*>(out0)[(size_t)(row0 + v) * Nn + col] =
              acc[fr][fc][v] + bias[col];
      }
  } else if (n0 < 1024) {
    // Q/K: two 32-KB LDS-transpose passes (wc halves) -> coalesced qkT stores.
    #pragma unroll
    for (int p = 0; p < 2; ++p) {
      __builtin_amdgcn_s_barrier();
      if (wc == p) {
        #pragma unroll
        for (int fr = 0; fr < 4; ++fr)
          #pragma unroll
          for (int fc = 0; fc < 4; ++fc) {
            const int tok = wr * 64 + fr * 16 + lg * 4;  // token-local, %4==0
            const int cl = fc * 16 + l15;                // col within 64-half
            ushort4 o;
            o.x = f2bfu(acc[fr][fc][0]);
            o.y = f2bfu(acc[fr][fc][1]);
            o.z = f2bfu(acc[fr][fc][2]);
            o.w = f2bfu(acc[fr][fc][3]);
            const int byte = cl * 512 + ((tok * 2) ^ ((cl & 7) << 4));
            *reinterpret_cast<ushort4*>(lds + byte) = o;
          }
      }
      __builtin_amdgcn_s_barrier();
      #pragma unroll
      for (int it = 0; it < 4; ++it) {
        const int cl = it * 16 + (tid >> 5);
        const int ns = (tid & 31) * 8;
        const int byte = cl * 512 + ((ns * 2) ^ ((cl & 7) << 4));
        short8 val = *reinterpret_cast<const short8*>(lds + byte);
        const int gcol = n0 + p * 64 + cl;
        const int sel = gcol >> 9, rem = gcol & 511;
        const int bh = (m0 >> 12) * 8 + (rem >> 6), cc = rem & 63;
        *reinterpret_cast<short8*>(&reinterpret_cast<unsigned short*>(out0)[
            ((size_t)sel * 4096 + bh * 64 + cc) * 4096 + (m0 & 4095) + ns]) = val;
      }
    }
  } else {
    // V block: direct vb[bh][n][d] stores
    #pragma unroll
    for (int fr = 0; fr < 4; ++fr)
      #pragma unroll
      for (int fc = 0; fc < 4; ++fc) {
        const int row0 = m0 + wr * 64 + fr * 16 + lg * 4;
        const int col = n0 + wc * 64 + fc * 16 + l15;
        const int rem = col & 511, hh = rem >> 6, cc = rem & 63;
        const int bb = row0 >> 12, nseq = row0 & 4095;
        const int bh = bb * 8 + hh;
        #pragma unroll
        for (int v = 0; v < 4; ++v)
          reinterpret_cast<unsigned short*>(out1)[
              ((size_t)bh * 4096 + nseq + v) * 64 + cc] =
              f2bfu(acc[fr][fc][v]);
      }
  }
}

// ---------------- attn QK^T via MFMA: rawp[s][bh][c][d] partials + norms ----------------
__global__ __launch_bounds__(256) void attn_qk(const unsigned short* __restrict__ qkT,
                                               float* __restrict__ rawp,
                                               float* __restrict__ normp) {
  const int bh = blockIdx.x, s = blockIdx.y;
  const int tid = threadIdx.x, w = tid >> 6, lane = tid & 63;
  const int l15 = lane & 15, lg = lane >> 4;
  const int nbase = s * 512 + w * 128;
  const unsigned short* qrow = qkT + (size_t)(bh * 64) * 4096;
  const unsigned short* krow = qkT + (size_t)(4096 + bh * 64) * 4096;

  __shared__ float red[4][64][64];
  __shared__ float nrm[4][2][64];

  f32x4 acc[4][4] = {};
  float sq[4] = {0.f, 0.f, 0.f, 0.f}, sk[4] = {0.f, 0.f, 0.f, 0.f};

  #pragma unroll
  for (int kc = 0; kc < 2; ++kc) {
    short8 aq[4][2], bk[4][2];
    #pragma unroll
    for (int fr = 0; fr < 4; ++fr)
      #pragma unroll
      for (int ks = 0; ks < 2; ++ks) {
        const size_t off = (size_t)(fr * 16 + l15) * 4096 + nbase + (kc * 2 + ks) * 32 + lg * 8;
        aq[fr][ks] = *reinterpret_cast<const short8*>(&qrow[off]);
        bk[fr][ks] = *reinterpret_cast<const short8*>(&krow[off]);
      }
    #pragma unroll
    for (int ks = 0; ks < 2; ++ks)
      #pragma unroll
      for (int fr = 0; fr < 4; ++fr)
        #pragma unroll
        for (int fc = 0; fc < 4; ++fc)
          acc[fr][fc] = __builtin_amdgcn_mfma_f32_16x16x32_bf16(
              aq[fr][ks], bk[fc][ks], acc[fr][fc], 0, 0, 0);
    #pragma unroll
    for (int fr = 0; fr < 4; ++fr)
      #pragma unroll
      for (int ks = 0; ks < 2; ++ks)
        #pragma unroll
        for (int j = 0; j < 8; ++j) {
          const float fq = bfu2f((unsigned short)aq[fr][ks][j]);
          const float fk = bfu2f((unsigned short)bk[fr][ks][j]);
          sq[fr] = fmaf(fq, fq, sq[fr]);
          sk[fr] = fmaf(fk, fk, sk[fr]);
        }
  }

  #pragma unroll
  for (int fr = 0; fr < 4; ++fr) {
    sq[fr] += __shfl_xor(sq[fr], 16); sq[fr] += __shfl_xor(sq[fr], 32);
    sk[fr] += __shfl_xor(sk[fr], 16); sk[fr] += __shfl_xor(sk[fr], 32);
  }
  if (lane < 16) {
    #pragma unroll
    for (int fr = 0; fr < 4; ++fr) {
      nrm[w][0][fr * 16 + lane] = sq[fr];
      nrm[w][1][fr * 16 + lane] = sk[fr];
    }
  }
  #pragma unroll
  for (int fr = 0; fr < 4; ++fr)
    #pragma unroll
    for (int fc = 0; fc < 4; ++fc)
      #pragma unroll
      for (int v = 0; v < 4; ++v)
        red[w][fr * 16 + lg * 4 + v][fc * 16 + l15] = acc[fr][fc][v];
  __syncthreads();

  const float* rf = &red[0][0][0];
  float* rp = rawp + ((size_t)s * 64 + bh) * 4096;
  for (int i = tid; i < 4096; i += 256)
    rp[i] = rf[i] + rf[4096 + i] + rf[8192 + i] + rf[12288 + i];
  const float* nf = &nrm[0][0][0];
  if (tid < 128) {
    float* np = normp + ((size_t)s * 64 + bh) * 128;
    np[tid] = nf[tid] + nf[128 + tid] + nf[256 + tid] + nf[384 + tid];
  }
}

// ---------------- finalize: reduce partials, normalize, softmax -> P (f32) --------------
__global__ __launch_bounds__(64) void attn_finalize(const float* __restrict__ rawp,
                                                    const float* __restrict__ normp,
                                                    const float* __restrict__ temperature,
                                                    float* __restrict__ Pmat) {
  const int bh = blockIdx.x, c8 = blockIdx.y, h = bh & 7;
  const int d = threadIdx.x;
  float nq = 0.f, nk = 0.f;
  for (int s = 0; s < NSPL; ++s) {
    nq += normp[((size_t)s * 64 + bh) * 128 + d];
    nk += normp[((size_t)s * 64 + bh) * 128 + 64 + d];
  }
  nq = fmaxf(sqrtf(nq), 1e-12f);
  nk = fmaxf(sqrtf(nk), 1e-12f);
  const float t = temperature[h];
  for (int i = 0; i < 8; ++i) {
    const int c = c8 * 8 + i;
    float r = 0.f;
    for (int s = 0; s < NSPL; ++s)
      r += rawp[((size_t)s * 64 + bh) * 4096 + c * 64 + d];
    const float nqc = __shfl(nq, c);
    float v = r * t / (nqc * nk);
    float m = v;
    #pragma unroll
    for (int off = 32; off > 0; off >>= 1) m = fmaxf(m, __shfl_xor(m, off));
    float e = __expf(v - m);
    float ssum = e;
    #pragma unroll
    for (int off = 32; off > 0; off >>= 1) ssum += __shfl_xor(ssum, off);
    Pmat[(size_t)bh * 4096 + c * 64 + d] = e / ssum;
  }
}

// --------- Wmod_bh[d][j] = sum_c P_bh[c][d] * Wp[h*64+c][j]; store transposed -----------
// WmodT[b][j][h*64+d] (bf16) so the final GEMM's Bt rows are K-major over k=h*64+d.
__global__ __launch_bounds__(256) void wmod_kernel(const float* __restrict__ Pmat,
                                                   const float* __restrict__ Wproj,
                                                   unsigned short* __restrict__ WmodT) {
  const int bh = blockIdx.x, jt = blockIdx.y;
  const int b = bh >> 3, h = bh & 7;
  const int tid = threadIdx.x;
  __shared__ float PL[64][64];
  __shared__ float WT[64][65];
  for (int i = tid; i < 4096; i += 256) PL[i >> 6][i & 63] = Pmat[(size_t)bh * 4096 + i];
  for (int i = tid; i < 4096; i += 256) {
    const int c = i >> 6, j = i & 63;
    WT[c][j] = Wproj[(size_t)(h * 64 + c) * 512 + jt * 64 + j];
  }
  __syncthreads();
  const int d = tid & 63, jq = tid >> 6;
  #pragma unroll
  for (int jl = jq * 16; jl < jq * 16 + 16; ++jl) {
    float acc = 0.f;
    #pragma unroll
    for (int c = 0; c < 64; ++c) acc = fmaf(PL[c][d], WT[c][jl], acc);
    WmodT[((size_t)b * 512 + jt * 64 + jl) * 512 + h * 64 + d] = f2bfu(acc);
  }
}

extern "C" void kernel_launch(void* const* d_in, const int* in_sizes, int n_in,
                              void* d_out, int out_size, void* d_ws, size_t ws_size,
                              hipStream_t stream) {
  const float* x = (const float*)d_in[0];
  const float* Wqkv = (const float*)d_in[2];
  const float* temp = (const float*)d_in[3];
  const float* Wproj = (const float*)d_in[4];
  const float* bproj = (const float*)d_in[5];
  float* out = (float*)d_out;

  char* w = (char*)d_ws;
  unsigned short* xb = (unsigned short*)w;    w += (size_t)MTOK * CH * 2;
  unsigned short* wqT = (unsigned short*)w;   w += (size_t)K3C * CH * 2;
  unsigned short* qkT = (unsigned short*)w;   w += (size_t)2 * 64 * 64 * 4096 * 2;
  unsigned short* vb = (unsigned short*)w;    w += (size_t)64 * 4096 * 64 * 2;
  float* rawp = (float*)w;                    w += (size_t)NSPL * 64 * 4096 * 4;
  float* normp = (float*)w;                   w += (size_t)NSPL * 64 * 128 * 4;
  float* Pmat = (float*)w;                    w += (size_t)64 * 4096 * 4;
  unsigned short* WmodT = (unsigned short*)w; w += (size_t)BQ * CH * CH * 2;

  cast_f32_bf16<<<2048, 256, 0, stream>>>(x, xb, MTOK * CH / 4);
  transpose_cast<<<dim3(K3C / 32, CH / 32), dim3(32, 8), 0, stream>>>(Wqkv, wqT, CH, K3C);
  gemm256<0><<<1536, 512, 0, stream>>>(xb, wqT, qkT, vb, nullptr, MTOK, K3C, CH, 12);
  attn_qk<<<dim3(64, 8), 256, 0, stream>>>(qkT, rawp, normp);
  attn_finalize<<<dim3(64, 8), 64, 0, stream>>>(rawp, normp, temp, Pmat);
  wmod_kernel<<<dim3(64, 8), 256, 0, stream>>>(Pmat, Wproj, WmodT);
  gemm256<2><<<512, 512, 0, stream>>>(vb, WmodT, out, nullptr, bproj, MTOK, CH, CH, 4);
}